// Round 1
// baseline (141.706 us; speedup 1.0000x reference)
//
#include <hip/hip_runtime.h>
#include <hip/hip_fp16.h>
#include <math.h>

#define BB 16
#define SS 256
#define CC 17
#define NCH 16
#define DD 32
#define DFFN 64
#define HH 4
#define DH 8
#define EE 4

// ws layout (4-byte units):
//  [16 ..143]  K0[e][d]   [144..271] V0[e][d]
//  [512..66047]  XNS[b][s][n]
//  ints at WS_SPI: SP[b][p] (4096), OFF[b][e] (64)
//  WS_WT: weight images (16384 uints): WqT/WkT/WvT 6144 | WoT 2048 | W1T 4096 | W2T 2x2048
#define WS_K0 16
#define WS_V0 144
#define WS_XNS 512
#define WS_SPI (WS_XNS + BB*SS*NCH)          // 66048
#define WS_WT  (WS_SPI + BB*SS + 64)         // 70208
#define WS_WL  (WS_WT + 6144)

#define PRE 0.51006977f   // (1/sqrt(8)) * log2(e)

typedef __fp16 hv2 __attribute__((ext_vector_type(2)));

__device__ __forceinline__ unsigned pkh2(float a, float b) {
  hv2 r = __builtin_amdgcn_cvt_pkrtz(a, b);
  unsigned u; __builtin_memcpy(&u, &r, 4);
  return u;
}
__device__ __forceinline__ float fd2(unsigned a, unsigned b, float c) {
  hv2 av, bv;
  __builtin_memcpy(&av, &a, 4);
  __builtin_memcpy(&bv, &b, 4);
  return __builtin_amdgcn_fdot2(av, bv, c, false);
}
__device__ __forceinline__ __half2 u2h2(unsigned u) {
  __half2 h; __builtin_memcpy(&h, &u, 4); return h;
}
__device__ __forceinline__ __half2 shx_h2(__half2 x, int m) {
  int v; __builtin_memcpy(&v, &x, 4);
  v = __shfl_xor(v, m);
  __half2 r; __builtin_memcpy(&r, &v, 4);
  return r;
}
template<int PAT>
__device__ __forceinline__ unsigned qdpp(unsigned v) {
  return (unsigned)__builtin_amdgcn_mov_dpp((int)v, PAT, 0xF, 0xF, true);
}
template<int PAT>
__device__ __forceinline__ float qdppf(float v) {
  return __uint_as_float(qdpp<PAT>(__float_as_uint(v)));
}

// ---------------------------------------------------------------------------
// Kernel 1 (1024 thr): decomp (blocks 0..255), prep (256..271),
// weight-image convert (272..275).  [unchanged]
// ---------------------------------------------------------------------------
__launch_bounds__(1024)
__global__ void decomp_prep_kernel(const float* __restrict__ x,
                                   const float* __restrict__ ox,
                                   const float* __restrict__ sb,
                                   const float* __restrict__ g1,
                                   const float* __restrict__ bb1,
                                   const float* __restrict__ Wq,
                                   const float* __restrict__ Wk,
                                   const float* __restrict__ Wv,
                                   const float* __restrict__ Wo,
                                   const float* __restrict__ W1,
                                   const float* __restrict__ W2,
                                   float* __restrict__ ws) {
  const int t = threadIdx.x;  // 1024
  if (blockIdx.x < 256) {
    const int b = blockIdx.x / NCH;
    const int c = blockIdx.x % NCH;
    __shared__ float xs[SS];
    __shared__ float prr[1024], pii[1024];
    __shared__ float amp[129];
    __shared__ float2 YY[129];
    __shared__ float sth;
    if (t < SS) xs[t] = x[(b*SS + t)*CC + c];
    __syncthreads();
    const float TH0 = 0.024543692606170259f;  // 2*pi/256
    {
      const int f = (t & 127) + 1;
      const int chunk = t >> 7;
      const int s0 = chunk * 32;
      const int ph0 = (f * s0) & 255;
      float si, cr; sincosf(TH0*(float)ph0, &si, &cr);
      float s1, c1; sincosf(TH0*(float)f, &s1, &c1);
      float xr = 0.f, xi = 0.f;
      #pragma unroll 4
      for (int k = 0; k < 32; ++k) {
        float xvv = xs[s0 + k];
        xr += xvv * cr;
        xi -= xvv * si;
        float nc = cr*c1 - si*s1;
        si = si*c1 + cr*s1;
        cr = nc;
      }
      prr[t] = xr; pii[t] = xi;
    }
    __syncthreads();
    if (t < 128) {
      float xr = 0.f, xi = 0.f;
      #pragma unroll
      for (int k2 = 0; k2 < 8; ++k2) { xr += prr[t + 128*k2]; xi += pii[t + 128*k2]; }
      prr[t] = xr; pii[t] = xi;
      amp[t+1] = sqrtf(xr*xr + xi*xi);
    }
    __syncthreads();
    if (t < 64) {   // wave 0: top-4 knockout
      float a0 = amp[t+1], a1 = amp[t+65];
      int i0 = t+1, i1 = t+65;
      float th = -1e30f;
      for (int r = 0; r < 4; ++r) {
        float mv = (a0 > a1) ? a0 : a1;
        int   mi = (a0 > a1) ? i0 : i1;
        for (int off = 32; off > 0; off >>= 1) {
          float ov = __shfl_xor(mv, off);
          int   oi = __shfl_xor(mi, off);
          if (ov > mv || (ov == mv && oi < mi)) { mv = ov; mi = oi; }
        }
        th = mv;
        if (mi == i0) a0 = -1e30f;
        if (mi == i1) a1 = -1e30f;
      }
      if (t == 0) sth = th;
    }
    __syncthreads();
    if (t < 128) {
      const int f = t + 1;
      float wgt = (amp[f] >= sth) ? ((f == 128) ? 1.0f : 2.0f) * (1.0f/256.0f) : 0.0f;
      YY[f] = make_float2(wgt * prr[t], wgt * pii[t]);
    }
    __syncthreads();
    {
      const int s = t & 255;
      const int fc = t >> 8;
      const int f0 = 1 + fc*32;
      const int ph0 = (s * f0) & 255;
      float si, cr; sincosf(TH0*(float)ph0, &si, &cr);
      float s1, c1; sincosf(TH0*(float)s, &s1, &c1);
      float acc = 0.f;
      #pragma unroll 4
      for (int k = 0; k < 32; ++k) {
        float2 y = YY[f0 + k];
        acc += y.x*cr - y.y*si;
        float nc = cr*c1 - si*s1;
        si = si*c1 + cr*s1;
        cr = nc;
      }
      prr[t] = acc;
    }
    __syncthreads();
    if (t < 256) {
      float season = prr[t] + prr[t+256] + prr[t+512] + prr[t+768];
      float s4 = 0.f, s8 = 0.f, s12 = 0.f;
      #pragma unroll
      for (int j = 0; j < 4; ++j)  { int p = t + j - 1; p = p < 0 ? 0 : (p > SS-1 ? SS-1 : p); s4  += xs[p]; }
      #pragma unroll
      for (int j = 0; j < 8; ++j)  { int p = t + j - 3; p = p < 0 ? 0 : (p > SS-1 ? SS-1 : p); s8  += xs[p]; }
      #pragma unroll
      for (int j = 0; j < 12; ++j) { int p = t + j - 5; p = p < 0 ? 0 : (p > SS-1 ? SS-1 : p); s12 += xs[p]; }
      float trend = (s4 * 0.25f + s8 * 0.125f + s12 * (1.0f/12.0f)) * (1.0f/3.0f);
      ws[WS_XNS + (b*SS + t)*NCH + c] = xs[t] + season + trend;
    }
  } else if (blockIdx.x < 272) {
    const int b = blockIdx.x - 256;
    __shared__ float red[32];
    __shared__ int asg[SS];
    __shared__ int cnt[EE];
    __shared__ float z0[EE*DD];
    float mn = 3e38f, mx = -3e38f;
    #pragma unroll
    for (int k = 0; k < 4; ++k) {
      float v = ox[(t + k*1024)*2 + 1];
      mn = fminf(mn, v); mx = fmaxf(mx, v);
    }
    for (int off = 32; off > 0; off >>= 1) {
      mn = fminf(mn, __shfl_xor(mn, off));
      mx = fmaxf(mx, __shfl_xor(mx, off));
    }
    if ((t & 63) == 0) { red[(t>>6)*2] = mn; red[(t>>6)*2+1] = mx; }
    __syncthreads();
    mn = red[0]; mx = red[1];
    #pragma unroll
    for (int w = 1; w < 16; ++w) { mn = fminf(mn, red[w*2]); mx = fmaxf(mx, red[w*2+1]); }
    const float step = (mx - mn) * 0.25f;
    const float e1 = mn + step, e2 = mn + 2.f*step, e3 = mn + 3.f*step;
    if (t < 256) {
      float sc = ox[(b*SS + t)*2 + 1];
      asg[t] = (sc >= e1) + (sc >= e2) + (sc >= e3);
    }
    __syncthreads();
    if (t < EE) {
      int c = 0;
      for (int s2 = 0; s2 < SS; ++s2) c += (asg[s2] == t);
      cnt[t] = c;
    }
    __syncthreads();
    int* SPw  = (int*)ws + WS_SPI;
    int* OFFw = SPw + BB*SS;
    if (t < EE) {
      int off = 0;
      for (int i = 0; i < t; ++i) off += cnt[i];
      OFFw[b*EE + t] = off;
      int kp = off;
      for (int s2 = 0; s2 < SS; ++s2) if (asg[s2] == t) SPw[b*SS + (kp++)] = s2;
    }
    if (t < 128) {
      int ee = t >> 5, d = t & 31;
      float m = 0.f;
      for (int i = 0; i < DD; ++i) m += sb[i];
      m *= (1.0f/DD);
      float var = 0.f;
      for (int i = 0; i < DD; ++i) { float df = sb[i]-m; var += df*df; }
      var *= (1.0f/DD);
      float rs = rsqrtf(var + 1e-5f);
      z0[ee*DD + d] = (sb[d]-m)*rs*g1[ee*DD+d] + bb1[ee*DD+d];
    }
    __syncthreads();
    if (b == 0 && t < 128) {
      int ee = t >> 5, d = t & 31;
      float k0 = 0.f, v0 = 0.f;
      for (int i = 0; i < DD; ++i) {
        float zz = z0[ee*DD + i];
        k0 += zz * Wk[ee*DD*DD + i*DD + d];
        v0 += zz * Wv[ee*DD*DD + i*DD + d];
      }
      ws[WS_K0 + ee*DD + d] = k0;
      ws[WS_V0 + ee*DD + d] = v0;
    }
  } else {
    unsigned* img = (unsigned*)ws + WS_WT;
    const int base_u = (blockIdx.x - 272)*4096;
    #pragma unroll
    for (int i = 0; i < 4; ++i) {
      int u = base_u + i*1024 + t;
      unsigned val;
      if (u < 6144) {                    // Wq/Wk/Wv T
        int mat = u >> 11, r = u & 2047;
        int row = r >> 4, ip = r & 15;
        int e = row >> 5, q = row & 31;
        int d = (q & 3)*8 + (q >> 2);
        const float* Wm = (mat == 0) ? Wq : (mat == 1) ? Wk : Wv;
        const float* src = Wm + e*1024 + d;
        val = pkh2(src[ip*64], src[ip*64 + 32]);
      } else {
        int v = u - 6144;
        if (v < 2048) {                  // WoT
          int row = v >> 4, ip = v & 15;
          int e = row >> 5, q = row & 31;
          int d = (q & 3)*8 + (q >> 2);
          const float* src = Wo + e*1024 + d;
          val = pkh2(src[ip*64], src[ip*64 + 32]);
        } else if (v < 6144) {           // W1T
          int r = v - 2048;
          int row = r >> 4, ip = r & 15;
          int e = row >> 6, q = row & 63;
          int j = (q & 3)*16 + (q >> 2);
          const float* src = W1 + e*2048 + j;
          val = pkh2(src[ip*128], src[ip*128 + 64]);
        } else {                         // W2T (two planes)
          int r = v - 6144;
          int a = r >> 11, rr = r & 2047;
          int row = rr >> 4, ip = rr & 15;
          int e = row >> 5, q = row & 31;
          int d = (q & 3)*8 + (q >> 2);
          int jp = a*16 + ip;
          const float* src = W2 + e*2048 + d;
          val = pkh2(src[2*jp*32], src[(2*jp+1)*32]);
        }
      }
      img[u] = val;
    }
  }
}

// ---------------------------------------------------------------------------
// Kernel 2: fused LN1+qkv+attn+Wo+LN2+FFN. Grid (b,n)=256 x 1024 thr.
// R11: 4-way split-K attention — the 4 positions of a lane-group {t,t^4,t^8,
// t^12} (same hh) share one stride-4 sweep over their expert's keys, so each
// ds_read_b128 of k/v serves 4 queries (attn LDS instruction traffic /4).
// k/v rows XOR-swizzled within their 128B row ((p&7)<<2 on uint idx) so the
// now-distinct row reads stay <=2-way bank aliased (free). Partials combined
// with a 2-round shfl_xor butterfly; boundary groups (mixed expert, <=3 per b)
// fall back to the old per-query path (butterfly still correct: partner
// partials are zero). Everything else unchanged from R10.
// ---------------------------------------------------------------------------
__launch_bounds__(1024, 4)
__global__ void fused_kernel(const float* __restrict__ ws,
    const float* __restrict__ g1, const float* __restrict__ bb1,
    const float* __restrict__ sW, const float* __restrict__ sb,
    const float* __restrict__ g2, const float* __restrict__ bb2,
    const float* __restrict__ b1, const float* __restrict__ b2,
    float* __restrict__ out) {
  const int blk = blockIdx.x;
  const int n = blk & 15;
  const int b = blk >> 4;
  const int t = threadIdx.x;
  const int p = t >> 2;         // sorted position 0..255
  const int hh = t & 3;
  __shared__ unsigned lds[24576];
  unsigned* wT = lds + 8192;
  unsigned* wl = lds + 14336;

  // async-stage both weight images (16384 uints = 64 x 1KB chunks, 4/wave)
  {
    const unsigned* img = (const unsigned*)ws + WS_WT;
    const int wv = t >> 6;
    const int ln = t & 63;
    #pragma unroll
    for (int i = 0; i < 4; ++i) {
      const int ch = wv*4 + i;
      __builtin_amdgcn_global_load_lds(
          (const __attribute__((address_space(1))) unsigned*)(img + ch*256 + ln*4),
          (__attribute__((address_space(3))) unsigned*)(wT + ch*256 + ln*4),
          16, 0, 0);
    }
  }

  const int* SP  = (const int*)ws + WS_SPI;
  const int* OFF = SP + BB*SS;
  const int o1 = OFF[b*4+1], o2v = OFF[b*4+2], o3 = OFF[b*4+3];
  const int e = (p >= o1) + (p >= o2v) + (p >= o3);
  const int beg = (e==0) ? 0  : ((e==1) ? o1 : ((e==2) ? o2v : o3));
  const int end = (e==0) ? o1 : ((e==1) ? o2v : ((e==2) ? o3 : SS));
  const int s = SP[b*SS + p];
  const float xv = ws[WS_XNS + (b*SS + s)*NCH + n];

  // LN1 (replicated x4 per position; cheap)
  float h[DD];
  #pragma unroll
  for (int d = 0; d < DD; ++d) h[d] = xv * sW[d] + sb[d];
  float m = 0.f;
  #pragma unroll
  for (int d = 0; d < DD; ++d) m += h[d];
  m *= (1.0f/DD);
  float var = 0.f;
  #pragma unroll
  for (int d = 0; d < DD; ++d) { float df = h[d]-m; var += df*df; }
  var *= (1.0f/DD);
  float rs = rsqrtf(var + 1e-5f);
  unsigned zp[16];
  #pragma unroll
  for (int ip = 0; ip < 16; ++ip) {
    float za = (h[2*ip]  -m)*rs*g1[e*DD+2*ip]   + bb1[e*DD+2*ip];
    float zb = (h[2*ip+1]-m)*rs*g1[e*DD+2*ip+1] + bb1[e*DD+2*ip+1];
    zp[ip] = pkh2(za, zb);
  }
  __syncthreads();   // barrier 1: weight images staged (vmcnt drained)

  // qkv for this (p, hh) slice via fdot2
  float q[DH], kk[DH], vv[DH];
  #pragma unroll
  for (int dd = 0; dd < DH; ++dd) {
    const int row16 = (e*32 + dd*4 + hh)*16;    // permuted rows: hh low bits
    const uint4* rq = (const uint4*)&wT[row16];
    const uint4* rk = (const uint4*)&wT[2048 + row16];
    const uint4* rv = (const uint4*)&wT[4096 + row16];
    float aq = 0.f, ak = 0.f, av = 0.f;
    #pragma unroll
    for (int g4 = 0; g4 < 4; ++g4) {
      uint4 wq4 = rq[g4], wk4 = rk[g4], wv4 = rv[g4];
      aq = fd2(zp[4*g4+0], wq4.x, aq); aq = fd2(zp[4*g4+1], wq4.y, aq);
      aq = fd2(zp[4*g4+2], wq4.z, aq); aq = fd2(zp[4*g4+3], wq4.w, aq);
      ak = fd2(zp[4*g4+0], wk4.x, ak); ak = fd2(zp[4*g4+1], wk4.y, ak);
      ak = fd2(zp[4*g4+2], wk4.z, ak); ak = fd2(zp[4*g4+3], wk4.w, ak);
      av = fd2(zp[4*g4+0], wv4.x, av); av = fd2(zp[4*g4+1], wv4.y, av);
      av = fd2(zp[4*g4+2], wv4.z, av); av = fd2(zp[4*g4+3], wv4.w, av);
    }
    q[dd] = aq * PRE; kk[dd] = ak; vv[dd] = av;
  }
  // write k/v to LDS (f16 packed, XOR-swizzled within the position's 128B row)
  const int kwidx = (p*32 + hh*8) ^ ((p & 7) << 2);
  *(uint4*)&lds[kwidx]     = make_uint4(pkh2(kk[0],kk[1]), pkh2(kk[2],kk[3]),
                                        pkh2(kk[4],kk[5]), pkh2(kk[6],kk[7]));
  *(uint4*)&lds[kwidx ^ 4] = make_uint4(pkh2(vv[0],vv[1]), pkh2(vv[2],vv[3]),
                                        pkh2(vv[4],vv[5]), pkh2(vv[6],vv[7]));
  unsigned qp2[4];
  #pragma unroll
  for (int i = 0; i < 4; ++i) qp2[i] = pkh2(q[2*i], q[2*i+1]);
  // group-mates' q: position p^d (same hh) lives at lane t^(4d)
  unsigned qx1[4], qx2[4], qx3[4];
  #pragma unroll
  for (int i = 0; i < 4; ++i) {
    qx1[i] = (unsigned)__shfl_xor((int)qp2[i], 4);
    qx2[i] = (unsigned)__shfl_xor((int)qp2[i], 8);
    qx3[i] = (unsigned)__shfl_xor((int)qp2[i], 12);
  }
  float s0 = 0.f;
  #pragma unroll
  for (int d = 0; d < DH; ++d) s0 += q[d] * ws[WS_K0 + e*DD + hh*DH + d];
  __syncthreads();   // barrier 2: kv staged — LAST barrier

  // ---- 4-way split-K attention over the position group {gb..gb+3} ----
  const int sl = p & 3;
  const int gb = p & ~3;
  const int egA = (gb     >= o1) + (gb     >= o2v) + (gb     >= o3);
  const int egB = ((gb+3) >= o1) + ((gb+3) >= o2v) + ((gb+3) >= o3);

  float ws0 = 0.f, ws1 = 0.f, ws2 = 0.f, ws3 = 0.f;
  __half2 oa0[4], oa1[4], oa2[4], oa3[4];
  #pragma unroll
  for (int j = 0; j < 4; ++j) {
    oa0[j] = u2h2(0u); oa1[j] = u2h2(0u);
    oa2[j] = u2h2(0u); oa3[j] = u2h2(0u);
  }

  if (egA == egB) {
    // whole group in one expert: stride-4 over keys, 4 queries per read
    for (int jk = beg + sl; jk < end; jk += 4) {
      const int kidx = (jk*32 + hh*8) ^ ((jk & 7) << 2);
      const uint4 ku = *(const uint4*)&lds[kidx];
      const uint4 vu = *(const uint4*)&lds[kidx ^ 4];
      float a0 = 0.f, a1 = 0.f, a2 = 0.f, a3 = 0.f;
      a0 = fd2(qp2[0], ku.x, a0); a0 = fd2(qp2[1], ku.y, a0);
      a0 = fd2(qp2[2], ku.z, a0); a0 = fd2(qp2[3], ku.w, a0);
      a1 = fd2(qx1[0], ku.x, a1); a1 = fd2(qx1[1], ku.y, a1);
      a1 = fd2(qx1[2], ku.z, a1); a1 = fd2(qx1[3], ku.w, a1);
      a2 = fd2(qx2[0], ku.x, a2); a2 = fd2(qx2[1], ku.y, a2);
      a2 = fd2(qx2[2], ku.z, a2); a2 = fd2(qx2[3], ku.w, a2);
      a3 = fd2(qx3[0], ku.x, a3); a3 = fd2(qx3[1], ku.y, a3);
      a3 = fd2(qx3[2], ku.z, a3); a3 = fd2(qx3[3], ku.w, a3);
      const float w0 = __builtin_amdgcn_exp2f(a0);
      const float w1 = __builtin_amdgcn_exp2f(a1);
      const float w2 = __builtin_amdgcn_exp2f(a2);
      const float w3 = __builtin_amdgcn_exp2f(a3);
      ws0 += w0; ws1 += w1; ws2 += w2; ws3 += w3;
      const __half2 hw0 = u2h2(pkh2(w0, w0));
      const __half2 hw1 = u2h2(pkh2(w1, w1));
      const __half2 hw2 = u2h2(pkh2(w2, w2));
      const __half2 hw3 = u2h2(pkh2(w3, w3));
      oa0[0] = __hfma2(hw0, u2h2(vu.x), oa0[0]);
      oa0[1] = __hfma2(hw0, u2h2(vu.y), oa0[1]);
      oa0[2] = __hfma2(hw0, u2h2(vu.z), oa0[2]);
      oa0[3] = __hfma2(hw0, u2h2(vu.w), oa0[3]);
      oa1[0] = __hfma2(hw1, u2h2(vu.x), oa1[0]);
      oa1[1] = __hfma2(hw1, u2h2(vu.y), oa1[1]);
      oa1[2] = __hfma2(hw1, u2h2(vu.z), oa1[2]);
      oa1[3] = __hfma2(hw1, u2h2(vu.w), oa1[3]);
      oa2[0] = __hfma2(hw2, u2h2(vu.x), oa2[0]);
      oa2[1] = __hfma2(hw2, u2h2(vu.y), oa2[1]);
      oa2[2] = __hfma2(hw2, u2h2(vu.z), oa2[2]);
      oa2[3] = __hfma2(hw2, u2h2(vu.w), oa2[3]);
      oa3[0] = __hfma2(hw3, u2h2(vu.x), oa3[0]);
      oa3[1] = __hfma2(hw3, u2h2(vu.y), oa3[1]);
      oa3[2] = __hfma2(hw3, u2h2(vu.z), oa3[2]);
      oa3[3] = __hfma2(hw3, u2h2(vu.w), oa3[3]);
    }
  } else {
    // boundary group (mixed experts): each lane does its own full range,
    // own-query only; partner partials stay zero so the butterfly is exact.
    for (int jk = beg; jk < end; ++jk) {
      const int kidx = (jk*32 + hh*8) ^ ((jk & 7) << 2);
      const uint4 ku = *(const uint4*)&lds[kidx];
      const uint4 vu = *(const uint4*)&lds[kidx ^ 4];
      float a0 = 0.f;
      a0 = fd2(qp2[0], ku.x, a0); a0 = fd2(qp2[1], ku.y, a0);
      a0 = fd2(qp2[2], ku.z, a0); a0 = fd2(qp2[3], ku.w, a0);
      const float w0 = __builtin_amdgcn_exp2f(a0);
      ws0 += w0;
      const __half2 hw0 = u2h2(pkh2(w0, w0));
      oa0[0] = __hfma2(hw0, u2h2(vu.x), oa0[0]);
      oa0[1] = __hfma2(hw0, u2h2(vu.y), oa0[1]);
      oa0[2] = __hfma2(hw0, u2h2(vu.z), oa0[2]);
      oa0[3] = __hfma2(hw0, u2h2(vu.w), oa0[3]);
    }
  }

  // butterfly combine across the group (only own-query output needed):
  // round1 (lane^4) pairs accumulator index d with d^1; round2 (lane^8) d with d^2.
  float wsum;
  {
    const float wA = ws0 + __shfl_xor(ws1, 4);
    const float wB = ws2 + __shfl_xor(ws3, 4);
    wsum = wA + __shfl_xor(wB, 8);
  }
  float o[DH];
  #pragma unroll
  for (int j = 0; j < 4; ++j) {
    const __half2 oA = __hadd2(oa0[j], shx_h2(oa1[j], 4));
    const __half2 oB = __hadd2(oa2[j], shx_h2(oa3[j], 4));
    const __half2 of = __hadd2(oA, shx_h2(oB, 8));
    o[2*j]   = __low2float(of);
    o[2*j+1] = __high2float(of);
  }

  // off-expert keys: constant score s0, constant value v0
  const int nmis = SS - (end - beg);
  float w0c = (float)nmis * __builtin_amdgcn_exp2f(s0);
  wsum += w0c;
  #pragma unroll
  for (int d = 0; d < DH; ++d) o[d] += w0c * ws[WS_V0 + e*DD + hh*DH + d];
  float inv = 1.0f / wsum;
  #pragma unroll
  for (int d = 0; d < DH; ++d) o[d] *= inv;

  // ---- o gather via DPP quad broadcast (no barrier, no LDS) ----
  unsigned oq[4];
  #pragma unroll
  for (int j = 0; j < 4; ++j) oq[j] = pkh2(o[2*j], o[2*j+1]);
  unsigned ovp[16];
  #pragma unroll
  for (int j = 0; j < 4; ++j) {
    ovp[j]    = qdpp<0x00>(oq[j]);
    ovp[4+j]  = qdpp<0x55>(oq[j]);
    ovp[8+j]  = qdpp<0xAA>(oq[j]);
    ovp[12+j] = qdpp<0xFF>(oq[j]);
  }

  // Wo + residual: acc[dd] = h2 at dim hh*8+dd
  float acc[DH];
  #pragma unroll
  for (int dd = 0; dd < DH; ++dd) {
    int d = hh*DH + dd;
    const uint4* row = (const uint4*)&wl[(e*32 + dd*4 + hh)*16];
    float a = xv * sW[d] + sb[d];
    #pragma unroll
    for (int g4 = 0; g4 < 4; ++g4) {
      uint4 w4 = row[g4];
      a = fd2(ovp[4*g4+0], w4.x, a); a = fd2(ovp[4*g4+1], w4.y, a);
      a = fd2(ovp[4*g4+2], w4.z, a); a = fd2(ovp[4*g4+3], w4.w, a);
    }
    acc[dd] = a;
  }

  // ---- LN2 via quad-sum DPP reductions ----
  float ssum = 0.f;
  #pragma unroll
  for (int dd = 0; dd < DH; ++dd) ssum += acc[dd];
  ssum += qdppf<0xB1>(ssum);
  ssum += qdppf<0x4E>(ssum);
  float m2 = ssum * (1.0f/DD);
  float vs = 0.f;
  #pragma unroll
  for (int dd = 0; dd < DH; ++dd) { float df = acc[dd]-m2; vs += df*df; }
  vs += qdppf<0xB1>(vs);
  vs += qdppf<0x4E>(vs);
  float rs2 = rsqrtf(vs * (1.0f/DD) + 1e-5f);
  unsigned zq[4];
  #pragma unroll
  for (int j = 0; j < 4; ++j) {
    int d = hh*DH + 2*j;
    float za = (acc[2*j]  -m2)*rs2*g2[e*DD+d]   + bb2[e*DD+d];
    float zb = (acc[2*j+1]-m2)*rs2*g2[e*DD+d+1] + bb2[e*DD+d+1];
    zq[j] = pkh2(za, zb);
  }
  unsigned zp2[16];
  #pragma unroll
  for (int j = 0; j < 4; ++j) {
    zp2[j]    = qdpp<0x00>(zq[j]);
    zp2[4+j]  = qdpp<0x55>(zq[j]);
    zp2[8+j]  = qdpp<0xAA>(zq[j]);
    zp2[12+j] = qdpp<0xFF>(zq[j]);
  }

  // FFN1: f[hh*16 .. +16)
  float f[16];
  #pragma unroll
  for (int jj = 0; jj < 16; ++jj) {
    const uint4* row = (const uint4*)&wl[2048 + (e*64 + jj*4 + hh)*16];
    float a = b1[e*DFFN + hh*16 + jj];
    #pragma unroll
    for (int g4 = 0; g4 < 4; ++g4) {
      uint4 w4 = row[g4];
      a = fd2(zp2[4*g4+0], w4.x, a); a = fd2(zp2[4*g4+1], w4.y, a);
      a = fd2(zp2[4*g4+2], w4.z, a); a = fd2(zp2[4*g4+3], w4.w, a);
    }
    f[jj] = fmaxf(a, 0.0f);
  }
  // ---- f gather via DPP quad broadcast ----
  unsigned fq[8];
  #pragma unroll
  for (int j = 0; j < 8; ++j) fq[j] = pkh2(f[2*j], f[2*j+1]);
  unsigned fu[32];
  #pragma unroll
  for (int j = 0; j < 8; ++j) {
    fu[j]    = qdpp<0x00>(fq[j]);
    fu[8+j]  = qdpp<0x55>(fq[j]);
    fu[16+j] = qdpp<0xAA>(fq[j]);
    fu[24+j] = qdpp<0xFF>(fq[j]);
  }

  // FFN2 + residual + b2
  float acc2[DH];
  #pragma unroll
  for (int dd = 0; dd < DH; ++dd) {
    int d = hh*DH + dd;
    const int row16 = (e*32 + dd*4 + hh)*16;
    float a = acc[dd] + b2[e*DD + d];
    #pragma unroll
    for (int g4 = 0; g4 < 8; ++g4) {
      const int plane = (g4 >> 2);
      uint4 w4 = *(const uint4*)&wl[6144 + plane*2048 + row16 + 4*(g4 & 3)];
      a = fd2(fu[4*g4+0], w4.x, a); a = fd2(fu[4*g4+1], w4.y, a);
      a = fd2(fu[4*g4+2], w4.z, a); a = fd2(fu[4*g4+3], w4.w, a);
    }
    acc2[dd] = a;
  }
  float* op = out + ((size_t)((b*SS + s)*NCH + n))*DD + hh*DH;
  *(float4*)(op)     = make_float4(acc2[0], acc2[1], acc2[2], acc2[3]);
  *(float4*)(op + 4) = make_float4(acc2[4], acc2[5], acc2[6], acc2[7]);
}

// ---------------------------------------------------------------------------
extern "C" void kernel_launch(void* const* d_in, const int* in_sizes, int n_in,
                              void* d_out, int out_size, void* d_ws, size_t ws_size,
                              hipStream_t stream) {
  (void)in_sizes; (void)n_in; (void)out_size; (void)ws_size;
  const float* x   = (const float*)d_in[0];
  const float* ox  = (const float*)d_in[1];
  const float* sW  = (const float*)d_in[2];
  const float* sb  = (const float*)d_in[3];
  const float* Wq  = (const float*)d_in[4];
  const float* Wk  = (const float*)d_in[5];
  const float* Wv  = (const float*)d_in[6];
  const float* Wo  = (const float*)d_in[7];
  const float* g1  = (const float*)d_in[8];
  const float* b1n = (const float*)d_in[9];
  const float* g2  = (const float*)d_in[10];
  const float* b2n = (const float*)d_in[11];
  const float* W1  = (const float*)d_in[12];
  const float* bf1 = (const float*)d_in[13];
  const float* W2  = (const float*)d_in[14];
  const float* bf2 = (const float*)d_in[15];
  float* out = (float*)d_out;
  float* ws  = (float*)d_ws;

  decomp_prep_kernel<<<276, 1024, 0, stream>>>(x, ox, sb, g1, b1n,
                                               Wq, Wk, Wv, Wo, W1, W2, ws);
  fused_kernel<<<BB*NCH, 1024, 0, stream>>>(ws, g1, b1n, sW, sb, g2, b2n,
                                            bf1, bf2, out);
}

// Round 2
// 135.566 us; speedup vs baseline: 1.0453x; 1.0453x over previous
//
#include <hip/hip_runtime.h>
#include <hip/hip_fp16.h>
#include <math.h>

#define BB 16
#define SS 256
#define CC 17
#define NCH 16
#define DD 32
#define DFFN 64
#define HH 4
#define DH 8
#define EE 4

// ws layout (4-byte units):
//  [8..10]     A,B,C LN1-collapse scalars
//  [16 ..143]  K0[e][d]   [144..271] V0[e][d]
//  [512..66047]  XNS[b][s][n]
//  ints at WS_SPI: SP[b][p] (4096), OFF[b][e] (64)
//  WS_WT: weight image (12288 uints):
//    [0,2048) WoT | [2048,6144) W1T | [6144,10240) W2T 2 planes
//    [10240,11392) PQR f32 (3 mats x 4 e x {P[32],Q[32],R[32]}) | pad to 12288
#define WS_K0 16
#define WS_V0 144
#define WS_XNS 512
#define WS_SPI (WS_XNS + BB*SS*NCH)          // 66048
#define WS_WT  (WS_SPI + BB*SS + 64)         // 70208

#define PRE 0.51006977f   // (1/sqrt(8)) * log2(e)

typedef __fp16 hv2 __attribute__((ext_vector_type(2)));

__device__ __forceinline__ unsigned pkh2(float a, float b) {
  hv2 r = __builtin_amdgcn_cvt_pkrtz(a, b);
  unsigned u; __builtin_memcpy(&u, &r, 4);
  return u;
}
__device__ __forceinline__ float fd2(unsigned a, unsigned b, float c) {
  hv2 av, bv;
  __builtin_memcpy(&av, &a, 4);
  __builtin_memcpy(&bv, &b, 4);
  return __builtin_amdgcn_fdot2(av, bv, c, false);
}
__device__ __forceinline__ __half2 u2h2(unsigned u) {
  __half2 h; __builtin_memcpy(&h, &u, 4); return h;
}
template<int PAT>
__device__ __forceinline__ unsigned qdpp(unsigned v) {
  return (unsigned)__builtin_amdgcn_mov_dpp((int)v, PAT, 0xF, 0xF, true);
}
template<int PAT>
__device__ __forceinline__ float qdppf(float v) {
  return __uint_as_float(qdpp<PAT>(__float_as_uint(v)));
}

// ---------------------------------------------------------------------------
// Kernel 1 (1024 thr): decomp (blocks 0..255), prep (256..271),
// weight-image convert (272..274), LN1-collapse PQR/ABC (275).
// ---------------------------------------------------------------------------
__launch_bounds__(1024)
__global__ void decomp_prep_kernel(const float* __restrict__ x,
                                   const float* __restrict__ ox,
                                   const float* __restrict__ sW,
                                   const float* __restrict__ sb,
                                   const float* __restrict__ g1,
                                   const float* __restrict__ bb1,
                                   const float* __restrict__ Wq,
                                   const float* __restrict__ Wk,
                                   const float* __restrict__ Wv,
                                   const float* __restrict__ Wo,
                                   const float* __restrict__ W1,
                                   const float* __restrict__ W2,
                                   float* __restrict__ ws) {
  const int t = threadIdx.x;  // 1024
  if (blockIdx.x < 256) {
    const int b = blockIdx.x / NCH;
    const int c = blockIdx.x % NCH;
    __shared__ float xs[SS];
    __shared__ float prr[1024], pii[1024];
    __shared__ float amp[129];
    __shared__ float2 YY[129];
    __shared__ float sth;
    if (t < SS) xs[t] = x[(b*SS + t)*CC + c];
    __syncthreads();
    const float TH0 = 0.024543692606170259f;  // 2*pi/256
    {
      const int f = (t & 127) + 1;
      const int chunk = t >> 7;
      const int s0 = chunk * 32;
      const int ph0 = (f * s0) & 255;
      float si, cr; sincosf(TH0*(float)ph0, &si, &cr);
      float s1, c1; sincosf(TH0*(float)f, &s1, &c1);
      float xr = 0.f, xi = 0.f;
      #pragma unroll 4
      for (int k = 0; k < 32; ++k) {
        float xvv = xs[s0 + k];
        xr += xvv * cr;
        xi -= xvv * si;
        float nc = cr*c1 - si*s1;
        si = si*c1 + cr*s1;
        cr = nc;
      }
      prr[t] = xr; pii[t] = xi;
    }
    __syncthreads();
    if (t < 128) {
      float xr = 0.f, xi = 0.f;
      #pragma unroll
      for (int k2 = 0; k2 < 8; ++k2) { xr += prr[t + 128*k2]; xi += pii[t + 128*k2]; }
      prr[t] = xr; pii[t] = xi;
      amp[t+1] = sqrtf(xr*xr + xi*xi);
    }
    __syncthreads();
    if (t < 64) {   // wave 0: top-4 knockout
      float a0 = amp[t+1], a1 = amp[t+65];
      int i0 = t+1, i1 = t+65;
      float th = -1e30f;
      for (int r = 0; r < 4; ++r) {
        float mv = (a0 > a1) ? a0 : a1;
        int   mi = (a0 > a1) ? i0 : i1;
        for (int off = 32; off > 0; off >>= 1) {
          float ov = __shfl_xor(mv, off);
          int   oi = __shfl_xor(mi, off);
          if (ov > mv || (ov == mv && oi < mi)) { mv = ov; mi = oi; }
        }
        th = mv;
        if (mi == i0) a0 = -1e30f;
        if (mi == i1) a1 = -1e30f;
      }
      if (t == 0) sth = th;
    }
    __syncthreads();
    if (t < 128) {
      const int f = t + 1;
      float wgt = (amp[f] >= sth) ? ((f == 128) ? 1.0f : 2.0f) * (1.0f/256.0f) : 0.0f;
      YY[f] = make_float2(wgt * prr[t], wgt * pii[t]);
    }
    __syncthreads();
    {
      const int s = t & 255;
      const int fc = t >> 8;
      const int f0 = 1 + fc*32;
      const int ph0 = (s * f0) & 255;
      float si, cr; sincosf(TH0*(float)ph0, &si, &cr);
      float s1, c1; sincosf(TH0*(float)s, &s1, &c1);
      float acc = 0.f;
      #pragma unroll 4
      for (int k = 0; k < 32; ++k) {
        float2 y = YY[f0 + k];
        acc += y.x*cr - y.y*si;
        float nc = cr*c1 - si*s1;
        si = si*c1 + cr*s1;
        cr = nc;
      }
      prr[t] = acc;
    }
    __syncthreads();
    if (t < 256) {
      float season = prr[t] + prr[t+256] + prr[t+512] + prr[t+768];
      float s4 = 0.f, s8 = 0.f, s12 = 0.f;
      #pragma unroll
      for (int j = 0; j < 4; ++j)  { int p = t + j - 1; p = p < 0 ? 0 : (p > SS-1 ? SS-1 : p); s4  += xs[p]; }
      #pragma unroll
      for (int j = 0; j < 8; ++j)  { int p = t + j - 3; p = p < 0 ? 0 : (p > SS-1 ? SS-1 : p); s8  += xs[p]; }
      #pragma unroll
      for (int j = 0; j < 12; ++j) { int p = t + j - 5; p = p < 0 ? 0 : (p > SS-1 ? SS-1 : p); s12 += xs[p]; }
      float trend = (s4 * 0.25f + s8 * 0.125f + s12 * (1.0f/12.0f)) * (1.0f/3.0f);
      ws[WS_XNS + (b*SS + t)*NCH + c] = xs[t] + season + trend;
    }
  } else if (blockIdx.x < 272) {
    const int b = blockIdx.x - 256;
    __shared__ float red[32];
    __shared__ int asg[SS];
    __shared__ int cnt[EE];
    __shared__ float z0[EE*DD];
    float mn = 3e38f, mx = -3e38f;
    #pragma unroll
    for (int k = 0; k < 4; ++k) {
      float v = ox[(t + k*1024)*2 + 1];
      mn = fminf(mn, v); mx = fmaxf(mx, v);
    }
    for (int off = 32; off > 0; off >>= 1) {
      mn = fminf(mn, __shfl_xor(mn, off));
      mx = fmaxf(mx, __shfl_xor(mx, off));
    }
    if ((t & 63) == 0) { red[(t>>6)*2] = mn; red[(t>>6)*2+1] = mx; }
    __syncthreads();
    mn = red[0]; mx = red[1];
    #pragma unroll
    for (int w = 1; w < 16; ++w) { mn = fminf(mn, red[w*2]); mx = fmaxf(mx, red[w*2+1]); }
    const float step = (mx - mn) * 0.25f;
    const float e1 = mn + step, e2 = mn + 2.f*step, e3 = mn + 3.f*step;
    if (t < 256) {
      float sc = ox[(b*SS + t)*2 + 1];
      asg[t] = (sc >= e1) + (sc >= e2) + (sc >= e3);
    }
    __syncthreads();
    if (t < EE) {
      int c = 0;
      for (int s2 = 0; s2 < SS; ++s2) c += (asg[s2] == t);
      cnt[t] = c;
    }
    __syncthreads();
    int* SPw  = (int*)ws + WS_SPI;
    int* OFFw = SPw + BB*SS;
    if (t < EE) {
      int off = 0;
      for (int i = 0; i < t; ++i) off += cnt[i];
      OFFw[b*EE + t] = off;
      int kp = off;
      for (int s2 = 0; s2 < SS; ++s2) if (asg[s2] == t) SPw[b*SS + (kp++)] = s2;
    }
    if (t < 128) {
      int ee = t >> 5, d = t & 31;
      float m = 0.f;
      for (int i = 0; i < DD; ++i) m += sb[i];
      m *= (1.0f/DD);
      float var = 0.f;
      for (int i = 0; i < DD; ++i) { float df = sb[i]-m; var += df*df; }
      var *= (1.0f/DD);
      float rs = rsqrtf(var + 1e-5f);
      z0[ee*DD + d] = (sb[d]-m)*rs*g1[ee*DD+d] + bb1[ee*DD+d];
    }
    __syncthreads();
    if (b == 0 && t < 128) {
      int ee = t >> 5, d = t & 31;
      float k0 = 0.f, v0 = 0.f;
      for (int i = 0; i < DD; ++i) {
        float zz = z0[ee*DD + i];
        k0 += zz * Wk[ee*DD*DD + i*DD + d];
        v0 += zz * Wv[ee*DD*DD + i*DD + d];
      }
      ws[WS_K0 + ee*DD + d] = k0;
      ws[WS_V0 + ee*DD + d] = v0;
    }
  } else if (blockIdx.x < 275) {
    // weight-image converters: 3 blocks x 4096 slots cover [0, 10240)
    unsigned* img = (unsigned*)ws + WS_WT;
    const int base_u = (blockIdx.x - 272)*4096;
    #pragma unroll
    for (int i = 0; i < 4; ++i) {
      int u = base_u + i*1024 + t;
      if (u < 10240) {
        unsigned val;
        if (u < 2048) {                  // WoT
          int row = u >> 4, ip = u & 15;
          int e = row >> 5, qq = row & 31;
          int d = (qq & 3)*8 + (qq >> 2);
          const float* src = Wo + e*1024 + d;
          val = pkh2(src[ip*64], src[ip*64 + 32]);
        } else if (u < 6144) {           // W1T
          int r = u - 2048;
          int row = r >> 4, ip = r & 15;
          int e = row >> 6, qq = row & 63;
          int j = (qq & 3)*16 + (qq >> 2);
          const float* src = W1 + e*2048 + j;
          val = pkh2(src[ip*128], src[ip*128 + 64]);
        } else {                         // W2T (two planes)
          int r = u - 6144;
          int a = r >> 11, rr = r & 2047;
          int row = rr >> 4, ip = rr & 15;
          int e = row >> 5, qq = row & 31;
          int d = (qq & 3)*8 + (qq >> 2);
          int jp = a*16 + ip;
          const float* src = W2 + e*2048 + d;
          val = pkh2(src[2*jp*32], src[(2*jp+1)*32]);
        }
        img[u] = val;
      }
    }
  } else {
    // block 275: LN1-collapse precompute.
    // h[d] = xv*sW[d]+sb[d]; mean = xv*mW+mb; h-mean = xv*a[d]+c[d]
    // var = xv^2*A + 2xv*B + C;  z = rs*(xv*a+c)*g1 + bb1
    // q[j] = alpha*P[j] + beta*Q[j] + R[j], alpha=rs*xv, beta=rs
    __shared__ float s_a[DD], s_c[DD];
    if (t < DD) { s_a[t] = sW[t]; s_c[t] = sb[t]; }
    __syncthreads();
    if (t == 0) {
      float mW = 0.f, mb = 0.f;
      for (int d = 0; d < DD; ++d) { mW += s_a[d]; mb += s_c[d]; }
      mW *= (1.0f/DD); mb *= (1.0f/DD);
      float A = 0.f, Bv = 0.f, Cv = 0.f;
      for (int d = 0; d < DD; ++d) {
        float a = s_a[d] - mW, c = s_c[d] - mb;
        s_a[d] = a; s_c[d] = c;
        A += a*a; Bv += a*c; Cv += c*c;
      }
      ws[8]  = A  * (1.0f/DD);
      ws[9]  = Bv * (1.0f/DD);
      ws[10] = Cv * (1.0f/DD);
    }
    __syncthreads();
    if (t < 384) {
      const int m = t >> 7, r = t & 127, e = r >> 5, j = r & 31;
      const float* Wm = (m == 0) ? Wq : (m == 1) ? Wk : Wv;
      float pp = 0.f, qq = 0.f, rr = 0.f;
      for (int d = 0; d < DD; ++d) {
        float w  = Wm[e*DD*DD + d*DD + j];
        float gg = g1[e*DD + d];
        pp += s_a[d]*gg*w;
        qq += s_c[d]*gg*w;
        rr += bb1[e*DD + d]*w;
      }
      float* pqr = ws + WS_WT + 10240;   // f32 view of image tail
      const int base = (m*EE + e)*96 + j;
      pqr[base]      = pp;
      pqr[base + 32] = qq;
      pqr[base + 64] = rr;
    }
  }
}

// ---------------------------------------------------------------------------
// Kernel 2: fused attn+Wo+LN2+FFN. Grid (b,n)=256 x 1024 thr.
// R12: LN1+QKV collapsed to alpha*P+beta*Q+R (precomputed per expert) —
// removes 384 fdot2 + 96 ds_read_b128 + the LN1 pass per thread; weight image
// shrinks 64->48 KB. Attention loop is EXACT R10 (broadcast reads, unroll-2);
// R11 split-K reverted (regressed +8us: de-broadcast + VGPR pressure).
// ---------------------------------------------------------------------------
__launch_bounds__(1024, 4)
__global__ void fused_kernel(const float* __restrict__ ws,
    const float* __restrict__ g1, const float* __restrict__ bb1,
    const float* __restrict__ sW, const float* __restrict__ sb,
    const float* __restrict__ g2, const float* __restrict__ bb2,
    const float* __restrict__ b1, const float* __restrict__ b2,
    float* __restrict__ out) {
  const int blk = blockIdx.x;
  const int n = blk & 15;
  const int b = blk >> 4;
  const int t = threadIdx.x;
  const int p = t >> 2;         // sorted position 0..255
  const int hh = t & 3;
  __shared__ unsigned lds[20480];    // [0,8192) kv | [8192,20480) weight image
  unsigned* wl = lds + 8192;

  // async-stage weight image (12288 uints = 48 x 1KB chunks, 3/wave)
  {
    const unsigned* img = (const unsigned*)ws + WS_WT;
    const int wv = t >> 6;
    const int ln = t & 63;
    #pragma unroll
    for (int i = 0; i < 3; ++i) {
      const int ch = wv*3 + i;
      __builtin_amdgcn_global_load_lds(
          (const __attribute__((address_space(1))) unsigned*)(img + ch*256 + ln*4),
          (__attribute__((address_space(3))) unsigned*)(wl + ch*256 + ln*4),
          16, 0, 0);
    }
  }

  const int* SP  = (const int*)ws + WS_SPI;
  const int* OFF = SP + BB*SS;
  const int o1 = OFF[b*4+1], o2v = OFF[b*4+2], o3 = OFF[b*4+3];
  const int e = (p >= o1) + (p >= o2v) + (p >= o3);
  const int beg = (e==0) ? 0  : ((e==1) ? o1 : ((e==2) ? o2v : o3));
  const int end = (e==0) ? o1 : ((e==1) ? o2v : ((e==2) ? o3 : SS));
  const int s = SP[b*SS + p];
  const float xv = ws[WS_XNS + (b*SS + s)*NCH + n];

  // LN1 collapse: var is a quadratic in xv
  const float Ac = ws[8], Bc = ws[9], Cc = ws[10];
  const float var = fmaf(xv, fmaf(Ac, xv, Bc + Bc), Cc);
  const float rs = rsqrtf(var + 1e-5f);
  const float alpha = rs * xv, beta = rs;
  __syncthreads();   // barrier 1: weight image staged (vmcnt drained)

  // qkv via precomputed PQR: q[dd] holds dim hh*8+dd
  const float* pqr = (const float*)(wl + 10240);
  float q[DH], kk[DH], vv[DH];
  #pragma unroll
  for (int m = 0; m < 3; ++m) {
    const float* bp = &pqr[(m*EE + e)*96 + hh*DH];
    const float4 P0 = *(const float4*)(bp);
    const float4 P1 = *(const float4*)(bp + 4);
    const float4 Q0 = *(const float4*)(bp + 32);
    const float4 Q1 = *(const float4*)(bp + 36);
    const float4 R0 = *(const float4*)(bp + 64);
    const float4 R1 = *(const float4*)(bp + 68);
    float* dst = (m == 0) ? q : (m == 1) ? kk : vv;
    dst[0] = fmaf(alpha, P0.x, fmaf(beta, Q0.x, R0.x));
    dst[1] = fmaf(alpha, P0.y, fmaf(beta, Q0.y, R0.y));
    dst[2] = fmaf(alpha, P0.z, fmaf(beta, Q0.z, R0.z));
    dst[3] = fmaf(alpha, P0.w, fmaf(beta, Q0.w, R0.w));
    dst[4] = fmaf(alpha, P1.x, fmaf(beta, Q1.x, R1.x));
    dst[5] = fmaf(alpha, P1.y, fmaf(beta, Q1.y, R1.y));
    dst[6] = fmaf(alpha, P1.z, fmaf(beta, Q1.z, R1.z));
    dst[7] = fmaf(alpha, P1.w, fmaf(beta, Q1.w, R1.w));
  }
  #pragma unroll
  for (int dd = 0; dd < DH; ++dd) q[dd] *= PRE;

  // write k/v to LDS (f16 packed)
  *(uint4*)&lds[p*32 + hh*8]     = make_uint4(pkh2(kk[0],kk[1]), pkh2(kk[2],kk[3]),
                                              pkh2(kk[4],kk[5]), pkh2(kk[6],kk[7]));
  *(uint4*)&lds[p*32 + hh*8 + 4] = make_uint4(pkh2(vv[0],vv[1]), pkh2(vv[2],vv[3]),
                                              pkh2(vv[4],vv[5]), pkh2(vv[6],vv[7]));
  unsigned qp2[4];
  #pragma unroll
  for (int i = 0; i < 4; ++i) qp2[i] = pkh2(q[2*i], q[2*i+1]);
  float s0 = 0.f;
  #pragma unroll
  for (int d = 0; d < DH; ++d) s0 += q[d] * ws[WS_K0 + e*DD + hh*DH + d];
  __syncthreads();   // barrier 2: kv staged — LAST barrier

  // attention: o accumulated as packed f16 pairs (v_pk_fma_f16)
  float wsum = 0.f;
  __half2 o2[4];
  #pragma unroll
  for (int i = 0; i < 4; ++i) o2[i] = u2h2(0u);
  int jk = beg;
  for (; jk + 1 < end; jk += 2) {
    uint4 ku0 = *(const uint4*)&lds[jk*32 + hh*8];
    uint4 vu0 = *(const uint4*)&lds[jk*32 + hh*8 + 4];
    uint4 ku1 = *(const uint4*)&lds[(jk+1)*32 + hh*8];
    uint4 vu1 = *(const uint4*)&lds[(jk+1)*32 + hh*8 + 4];
    float a0 = 0.f, a1 = 0.f;
    a0 = fd2(qp2[0], ku0.x, a0); a0 = fd2(qp2[1], ku0.y, a0);
    a0 = fd2(qp2[2], ku0.z, a0); a0 = fd2(qp2[3], ku0.w, a0);
    a1 = fd2(qp2[0], ku1.x, a1); a1 = fd2(qp2[1], ku1.y, a1);
    a1 = fd2(qp2[2], ku1.z, a1); a1 = fd2(qp2[3], ku1.w, a1);
    float w0f = __builtin_amdgcn_exp2f(a0);
    float w1f = __builtin_amdgcn_exp2f(a1);
    wsum += w0f + w1f;
    __half2 w20 = u2h2(pkh2(w0f, w0f));
    __half2 w21 = u2h2(pkh2(w1f, w1f));
    o2[0] = __hfma2(w20, u2h2(vu0.x), o2[0]);
    o2[1] = __hfma2(w20, u2h2(vu0.y), o2[1]);
    o2[2] = __hfma2(w20, u2h2(vu0.z), o2[2]);
    o2[3] = __hfma2(w20, u2h2(vu0.w), o2[3]);
    o2[0] = __hfma2(w21, u2h2(vu1.x), o2[0]);
    o2[1] = __hfma2(w21, u2h2(vu1.y), o2[1]);
    o2[2] = __hfma2(w21, u2h2(vu1.z), o2[2]);
    o2[3] = __hfma2(w21, u2h2(vu1.w), o2[3]);
  }
  if (jk < end) {
    uint4 ku = *(const uint4*)&lds[jk*32 + hh*8];
    uint4 vu = *(const uint4*)&lds[jk*32 + hh*8 + 4];
    float a = 0.f;
    a = fd2(qp2[0], ku.x, a); a = fd2(qp2[1], ku.y, a);
    a = fd2(qp2[2], ku.z, a); a = fd2(qp2[3], ku.w, a);
    float wf = __builtin_amdgcn_exp2f(a);
    wsum += wf;
    __half2 w2 = u2h2(pkh2(wf, wf));
    o2[0] = __hfma2(w2, u2h2(vu.x), o2[0]);
    o2[1] = __hfma2(w2, u2h2(vu.y), o2[1]);
    o2[2] = __hfma2(w2, u2h2(vu.z), o2[2]);
    o2[3] = __hfma2(w2, u2h2(vu.w), o2[3]);
  }
  // off-expert keys: constant score s0, constant value v0
  float o[DH];
  #pragma unroll
  for (int i = 0; i < 4; ++i) {
    o[2*i]   = __low2float(o2[i]);
    o[2*i+1] = __high2float(o2[i]);
  }
  const int nmis = SS - (end - beg);
  float w0 = (float)nmis * __builtin_amdgcn_exp2f(s0);
  wsum += w0;
  #pragma unroll
  for (int d = 0; d < DH; ++d) o[d] += w0 * ws[WS_V0 + e*DD + hh*DH + d];
  float inv = 1.0f / wsum;
  #pragma unroll
  for (int d = 0; d < DH; ++d) o[d] *= inv;

  // ---- o gather via DPP quad broadcast (no barrier, no LDS) ----
  unsigned oq[4];
  #pragma unroll
  for (int j = 0; j < 4; ++j) oq[j] = pkh2(o[2*j], o[2*j+1]);
  unsigned ovp[16];
  #pragma unroll
  for (int j = 0; j < 4; ++j) {
    ovp[j]    = qdpp<0x00>(oq[j]);
    ovp[4+j]  = qdpp<0x55>(oq[j]);
    ovp[8+j]  = qdpp<0xAA>(oq[j]);
    ovp[12+j] = qdpp<0xFF>(oq[j]);
  }

  // Wo + residual: acc[dd] = h2 at dim hh*8+dd
  float acc[DH];
  #pragma unroll
  for (int dd = 0; dd < DH; ++dd) {
    int d = hh*DH + dd;
    const uint4* row = (const uint4*)&wl[(e*32 + dd*4 + hh)*16];
    float a = xv * sW[d] + sb[d];
    #pragma unroll
    for (int g4 = 0; g4 < 4; ++g4) {
      uint4 w4 = row[g4];
      a = fd2(ovp[4*g4+0], w4.x, a); a = fd2(ovp[4*g4+1], w4.y, a);
      a = fd2(ovp[4*g4+2], w4.z, a); a = fd2(ovp[4*g4+3], w4.w, a);
    }
    acc[dd] = a;
  }

  // ---- LN2 via quad-sum DPP reductions ----
  float ssum = 0.f;
  #pragma unroll
  for (int dd = 0; dd < DH; ++dd) ssum += acc[dd];
  ssum += qdppf<0xB1>(ssum);
  ssum += qdppf<0x4E>(ssum);
  float m2 = ssum * (1.0f/DD);
  float vs = 0.f;
  #pragma unroll
  for (int dd = 0; dd < DH; ++dd) { float df = acc[dd]-m2; vs += df*df; }
  vs += qdppf<0xB1>(vs);
  vs += qdppf<0x4E>(vs);
  float rs2 = rsqrtf(vs * (1.0f/DD) + 1e-5f);
  unsigned zq[4];
  #pragma unroll
  for (int j = 0; j < 4; ++j) {
    int d = hh*DH + 2*j;
    float za = (acc[2*j]  -m2)*rs2*g2[e*DD+d]   + bb2[e*DD+d];
    float zb = (acc[2*j+1]-m2)*rs2*g2[e*DD+d+1] + bb2[e*DD+d+1];
    zq[j] = pkh2(za, zb);
  }
  unsigned zp2[16];
  #pragma unroll
  for (int j = 0; j < 4; ++j) {
    zp2[j]    = qdpp<0x00>(zq[j]);
    zp2[4+j]  = qdpp<0x55>(zq[j]);
    zp2[8+j]  = qdpp<0xAA>(zq[j]);
    zp2[12+j] = qdpp<0xFF>(zq[j]);
  }

  // FFN1: f[hh*16 .. +16)
  float f[16];
  #pragma unroll
  for (int jj = 0; jj < 16; ++jj) {
    const uint4* row = (const uint4*)&wl[2048 + (e*64 + jj*4 + hh)*16];
    float a = b1[e*DFFN + hh*16 + jj];
    #pragma unroll
    for (int g4 = 0; g4 < 4; ++g4) {
      uint4 w4 = row[g4];
      a = fd2(zp2[4*g4+0], w4.x, a); a = fd2(zp2[4*g4+1], w4.y, a);
      a = fd2(zp2[4*g4+2], w4.z, a); a = fd2(zp2[4*g4+3], w4.w, a);
    }
    f[jj] = fmaxf(a, 0.0f);
  }
  // ---- f gather via DPP quad broadcast ----
  unsigned fq[8];
  #pragma unroll
  for (int j = 0; j < 8; ++j) fq[j] = pkh2(f[2*j], f[2*j+1]);
  unsigned fu[32];
  #pragma unroll
  for (int j = 0; j < 8; ++j) {
    fu[j]    = qdpp<0x00>(fq[j]);
    fu[8+j]  = qdpp<0x55>(fq[j]);
    fu[16+j] = qdpp<0xAA>(fq[j]);
    fu[24+j] = qdpp<0xFF>(fq[j]);
  }

  // FFN2 + residual + b2
  float acc2[DH];
  #pragma unroll
  for (int dd = 0; dd < DH; ++dd) {
    int d = hh*DH + dd;
    const int row16 = (e*32 + dd*4 + hh)*16;
    float a = acc[dd] + b2[e*DD + d];
    #pragma unroll
    for (int g4 = 0; g4 < 8; ++g4) {
      const int plane = (g4 >> 2);
      uint4 w4 = *(const uint4*)&wl[6144 + plane*2048 + row16 + 4*(g4 & 3)];
      a = fd2(fu[4*g4+0], w4.x, a); a = fd2(fu[4*g4+1], w4.y, a);
      a = fd2(fu[4*g4+2], w4.z, a); a = fd2(fu[4*g4+3], w4.w, a);
    }
    acc2[dd] = a;
  }
  float* op = out + ((size_t)((b*SS + s)*NCH + n))*DD + hh*DH;
  *(float4*)(op)     = make_float4(acc2[0], acc2[1], acc2[2], acc2[3]);
  *(float4*)(op + 4) = make_float4(acc2[4], acc2[5], acc2[6], acc2[7]);
}

// ---------------------------------------------------------------------------
extern "C" void kernel_launch(void* const* d_in, const int* in_sizes, int n_in,
                              void* d_out, int out_size, void* d_ws, size_t ws_size,
                              hipStream_t stream) {
  (void)in_sizes; (void)n_in; (void)out_size; (void)ws_size;
  const float* x   = (const float*)d_in[0];
  const float* ox  = (const float*)d_in[1];
  const float* sW  = (const float*)d_in[2];
  const float* sb  = (const float*)d_in[3];
  const float* Wq  = (const float*)d_in[4];
  const float* Wk  = (const float*)d_in[5];
  const float* Wv  = (const float*)d_in[6];
  const float* Wo  = (const float*)d_in[7];
  const float* g1  = (const float*)d_in[8];
  const float* b1n = (const float*)d_in[9];
  const float* g2  = (const float*)d_in[10];
  const float* b2n = (const float*)d_in[11];
  const float* W1  = (const float*)d_in[12];
  const float* bf1 = (const float*)d_in[13];
  const float* W2  = (const float*)d_in[14];
  const float* bf2 = (const float*)d_in[15];
  float* out = (float*)d_out;
  float* ws  = (float*)d_ws;

  decomp_prep_kernel<<<276, 1024, 0, stream>>>(x, ox, sW, sb, g1, b1n,
                                               Wq, Wk, Wv, Wo, W1, W2, ws);
  fused_kernel<<<BB*NCH, 1024, 0, stream>>>(ws, g1, b1n, sW, sb, g2, b2n,
                                            bf1, bf2, out);
}